// Round 8
// baseline (718.641 us; speedup 1.0000x reference)
//
#include <hip/hip_runtime.h>
#include <stdint.h>

#define NB 64
#define DD 256
#define HH 512
#define NGROUP 2048

typedef __attribute__((ext_vector_type(8))) _Float16 half8;
typedef __attribute__((ext_vector_type(4))) _Float16 half4;
typedef __attribute__((ext_vector_type(4))) float f32x4;
typedef __attribute__((ext_vector_type(16))) float f32x16;

__device__ __forceinline__ half8 ld8(const _Float16* p) {
    return *reinterpret_cast<const half8*>(p);
}

// ---------------- merged prep kernel (validated R7) ----------------
__global__ void prep_all(const float* __restrict__ Wq1, const float* __restrict__ Wk1,
                         const float* __restrict__ Wv1, const float* __restrict__ Wq2,
                         const float* __restrict__ Wk2, const float* __restrict__ Wv2,
                         const float* __restrict__ W1, const float* __restrict__ W2,
                         _Float16* __restrict__ G1, _Float16* __restrict__ G2,
                         _Float16* __restrict__ UT, _Float16* __restrict__ W2T,
                         float scale) {
    const int b = blockIdx.x, t = threadIdx.x;
    if (b < 512) {
        const float* A = (b < 256) ? Wq1 : Wq2;
        const float* Bm = (b < 256) ? Wk2 : Wk1;
        _Float16* G = (b < 256) ? G1 : G2;
        const int d = b & 255, e = t;
        const float4* qa = reinterpret_cast<const float4*>(A + d * HH);
        const float4* ka = reinterpret_cast<const float4*>(Bm + e * HH);
        float s = 0.f;
        #pragma unroll 8
        for (int j = 0; j < HH / 4; ++j) {
            float4 a = qa[j], bb = ka[j];
            s += a.x * bb.x + a.y * bb.y + a.z * bb.z + a.w * bb.w;
        }
        G[d * DD + e] = (_Float16)(s * scale);
    } else if (b < 1536) {
        const int half = (b - 512) >> 9;
        const int o = (b - 512) & 511;
        const float* Wv = half ? Wv2 : Wv1;
        const float* W1p = W1 + half * HH * HH;
        const int d = t;
        const float4* va = reinterpret_cast<const float4*>(Wv + d * HH);
        float s = 0.f;
        #pragma unroll 4
        for (int j4 = 0; j4 < HH / 4; ++j4) {
            float4 a = va[j4];
            const int j = j4 * 4;
            s += a.x * W1p[(j + 0) * HH + o];
            s += a.y * W1p[(j + 1) * HH + o];
            s += a.z * W1p[(j + 2) * HH + o];
            s += a.w * W1p[(j + 3) * HH + o];
        }
        UT[o * HH + half * 256 + d] = (_Float16)s;
    } else {
        __shared__ float tile[32][33];
        const int bi = b - 1536;
        const int bk = (bi & 15) * 32;
        const int bh = (bi >> 4) * 32;
        const int tx = t & 31, ty = t >> 5;
        #pragma unroll
        for (int i = 0; i < 32; i += 8)
            tile[ty + i][tx] = W2[(bh + ty + i) * HH + bk + tx];
        __syncthreads();
        #pragma unroll
        for (int i = 0; i < 32; i += 8)
            W2T[(bk + ty + i) * HH + bh + tx] = (_Float16)tile[tx][ty + i];
    }
}

// ---------------- main fused kernel ----------------
// 512 thr (8 waves), 160 KiB LDS, 1 blk/CU; 32x32x16 MFMA in heavy phases.
// LDS:
//   X1  @ 0      [64][256] f16 (512B rows, full swz) -> g1
//   X2  @ 32768  same -> g2
//   XT1 @ 65536  X1^T packed [128][256B rows] (d-pairs)
//   XT2 @ 98304  same
//   R   @ 131072 32KB: scores A-chunk dbuf [2][2][64][64] | P1/P2 | h [64][256]
#define LDS_XT 65536
#define LDS_R  131072

// 512B-row buffers: extended swizzle (16B granule + 128B flip)
__device__ __forceinline__ int axX(int side, int row, int ec) {
    return side * 32768 + row * 512 +
           ((2 * ec) ^ ((row & 7) << 4) ^ (((row >> 3) & 1) << 7));
}
__device__ __forceinline__ int axH2(int row, int ec) {   // h [64][256] @R
    return LDS_R + row * 512 +
           ((2 * ec) ^ ((row & 7) << 4) ^ (((row >> 3) & 1) << 7));
}
// XT packed: element (d, m) at row d>>1 (256B rows), col (d&1)*64+m
__device__ __forceinline__ int axXT(int side, int d, int m) {
    const int row = d >> 1;
    return LDS_XT + side * 32768 + row * 256 +
           ((((d & 1) * 128 + 2 * m)) ^ ((row & 7) << 4) ^ (((row >> 3) & 1) << 7));
}
// A-chunk dbuf [buf][side][64][64] (128B rows)
__device__ __forceinline__ int axA(int buf, int side, int row, int ec) {
    return LDS_R + buf * 16384 + side * 8192 + row * 128 + ((2 * ec) ^ ((row & 7) << 4));
}
// P [side][64][64] (over A-chunk buf0)
__device__ __forceinline__ int axP(int side, int row, int ec) {
    return LDS_R + side * 8192 + row * 128 + ((2 * ec) ^ ((row & 7) << 4));
}

__global__ __launch_bounds__(512, 2)
void fused_kernel(const float* __restrict__ x1g, const float* __restrict__ x2g,
                  const _Float16* __restrict__ G1, const _Float16* __restrict__ G2,
                  const _Float16* __restrict__ UT, const _Float16* __restrict__ W2T,
                  const float* __restrict__ b1, const float* __restrict__ b2,
                  float* __restrict__ out) {
    __shared__ __align__(16) char lds[163840];

    const int tid = threadIdx.x;
    const int lane = tid & 63;
    const int w = tid >> 6;          // 0..7
    const int c = lane & 15;         // 16x16 indexing
    const int kg4 = lane >> 4;
    const int c5 = lane & 31;        // 32x32 indexing
    const int kg2 = lane >> 5;
    const int s = w >> 2;            // side (0:S1/P1/g1, 1:S2/P2/g2)
    const int wa = w & 3;
    const size_t g = blockIdx.x;
    const f32x4 z = {0.f, 0.f, 0.f, 0.f};
    const f32x16 z16 = {0.f,0.f,0.f,0.f,0.f,0.f,0.f,0.f,0.f,0.f,0.f,0.f,0.f,0.f,0.f,0.f};
    #define ROWF(r) ((((r) & 3) + 8 * ((r) >> 2)) + 4 * kg2)

    // ---- Phase 0a: stage x -> f16 LDS ----
    {
        const float* xs0 = x1g + g * (NB * DD);
        const float* xs1 = x2g + g * (NB * DD);
        #pragma unroll
        for (int it = 0; it < 8; ++it) {
            const int row = 8 * w + it;
            float4 a = reinterpret_cast<const float4*>(xs0 + row * DD)[lane];
            float4 b = reinterpret_cast<const float4*>(xs1 + row * DD)[lane];
            half4 ha, hb;
            ha[0] = (_Float16)a.x; ha[1] = (_Float16)a.y; ha[2] = (_Float16)a.z; ha[3] = (_Float16)a.w;
            hb[0] = (_Float16)b.x; hb[1] = (_Float16)b.y; hb[2] = (_Float16)b.z; hb[3] = (_Float16)b.w;
            *reinterpret_cast<half4*>(lds + axX(0, row, 4 * lane)) = ha;
            *reinterpret_cast<half4*>(lds + axX(1, row, 4 * lane)) = hb;
        }
    }
    __syncthreads();

    // ---- Phase 0b: build XT (packed) once ----
    {
        #pragma unroll
        for (int jj = 0; jj < 8; ++jj) {
            half8 v = *reinterpret_cast<const half8*>(lds + axX(s, lane, 64 * wa + 8 * jj));
            #pragma unroll
            for (int e = 0; e < 8; ++e)
                *reinterpret_cast<_Float16*>(lds + axXT(s, 64 * wa + 8 * jj + e, lane)) = v[e];
        }
    }
    __syncthreads();

    // ---- Scores: 4 rounds, A-chunk (32x32) + S partial (16x16, R7-proven) ----
    f32x4 Sacc[4] = {z, z, z, z};
    {
        const _Float16* Gsel = s ? G2 : G1;
        const int xo = 1 - s;          // A-source
        const int rb = wa & 1, cb = wa >> 1;
        #pragma unroll
        for (int ci = 0; ci < 4; ++ci) {
            const int buf = ci & 1;
            f32x16 ca = z16;
            const _Float16* gp = Gsel + (size_t)(64 * ci + 32 * cb + c5) * DD;
            #pragma unroll
            for (int ks = 0; ks < 16; ++ks) {
                half8 afr = *reinterpret_cast<const half8*>(lds + axX(xo, 32 * rb + c5, 16 * ks + 8 * kg2));
                half8 bfr = ld8(gp + 16 * ks + 8 * kg2);
                ca = __builtin_amdgcn_mfma_f32_32x32x16_f16(afr, bfr, ca, 0, 0, 0);
            }
            #pragma unroll
            for (int r = 0; r < 16; ++r)
                *reinterpret_cast<_Float16*>(lds + axA(buf, s, 32 * rb + ROWF(r), 32 * cb + c5)) = (_Float16)ca[r];
            __syncthreads();
            // S partial (16x16): rows 16wa.., K=64 of this chunk
            #pragma unroll
            for (int ks = 0; ks < 2; ++ks) {
                half8 af = *reinterpret_cast<const half8*>(lds + axX(s, 16 * wa + c, 64 * ci + 32 * ks + 8 * kg4));
                #pragma unroll
                for (int j = 0; j < 4; ++j) {
                    half8 bfr = *reinterpret_cast<const half8*>(lds + axA(buf, s, 16 * j + c, 32 * ks + 8 * kg4));
                    Sacc[j] = __builtin_amdgcn_mfma_f32_16x16x32_f16(af, bfr, Sacc[j], 0, 0, 0);
                }
            }
        }
    }

    // ---- Softmax (R7-proven) -> P[s] ----
    {
        #pragma unroll
        for (int r = 0; r < 4; ++r) {
            float m0 = fmaxf(fmaxf(Sacc[0][r], Sacc[1][r]), fmaxf(Sacc[2][r], Sacc[3][r]));
            m0 = fmaxf(m0, __shfl_xor(m0, 1));
            m0 = fmaxf(m0, __shfl_xor(m0, 2));
            m0 = fmaxf(m0, __shfl_xor(m0, 4));
            m0 = fmaxf(m0, __shfl_xor(m0, 8));
            float e0 = __expf(Sacc[0][r] - m0);
            float e1 = __expf(Sacc[1][r] - m0);
            float e2 = __expf(Sacc[2][r] - m0);
            float e3 = __expf(Sacc[3][r] - m0);
            float s0 = e0 + e1 + e2 + e3;
            s0 += __shfl_xor(s0, 1);
            s0 += __shfl_xor(s0, 2);
            s0 += __shfl_xor(s0, 4);
            s0 += __shfl_xor(s0, 8);
            const float inv = 1.f / s0;
            const int row = 16 * wa + 4 * kg4 + r;
            *reinterpret_cast<_Float16*>(lds + axP(s, row, 16 * 0 + c)) = (_Float16)(e0 * inv);
            *reinterpret_cast<_Float16*>(lds + axP(s, row, 16 * 1 + c)) = (_Float16)(e1 * inv);
            *reinterpret_cast<_Float16*>(lds + axP(s, row, 16 * 2 + c)) = (_Float16)(e2 * inv);
            *reinterpret_cast<_Float16*>(lds + axP(s, row, 16 * 3 + c)) = (_Float16)(e3 * inv);
        }
    }
    __syncthreads();

    // ---- PV (32x32): g[s] = P[s] @ X[s] via packed XT; g overwrites X[s] ----
    {
        const int rb = wa & 1;
        const int cb0 = (wa >> 1) * 4;
        f32x16 g0 = z16, g1 = z16, g2 = z16, g3 = z16;
        #pragma unroll
        for (int ks = 0; ks < 4; ++ks) {
            half8 pa = *reinterpret_cast<const half8*>(lds + axP(s, 32 * rb + c5, 16 * ks + 8 * kg2));
            half8 x0 = *reinterpret_cast<const half8*>(lds + axXT(s, 32 * (cb0 + 0) + c5, 16 * ks + 8 * kg2));
            half8 x1 = *reinterpret_cast<const half8*>(lds + axXT(s, 32 * (cb0 + 1) + c5, 16 * ks + 8 * kg2));
            half8 x2 = *reinterpret_cast<const half8*>(lds + axXT(s, 32 * (cb0 + 2) + c5, 16 * ks + 8 * kg2));
            half8 x3 = *reinterpret_cast<const half8*>(lds + axXT(s, 32 * (cb0 + 3) + c5, 16 * ks + 8 * kg2));
            g0 = __builtin_amdgcn_mfma_f32_32x32x16_f16(pa, x0, g0, 0, 0, 0);
            g1 = __builtin_amdgcn_mfma_f32_32x32x16_f16(pa, x1, g1, 0, 0, 0);
            g2 = __builtin_amdgcn_mfma_f32_32x32x16_f16(pa, x2, g2, 0, 0, 0);
            g3 = __builtin_amdgcn_mfma_f32_32x32x16_f16(pa, x3, g3, 0, 0, 0);
        }
        #pragma unroll
        for (int r = 0; r < 16; ++r) {
            const int grow = 32 * rb + ROWF(r);
            *reinterpret_cast<_Float16*>(lds + axX(s, grow, 32 * (cb0 + 0) + c5)) = (_Float16)g0[r];
            *reinterpret_cast<_Float16*>(lds + axX(s, grow, 32 * (cb0 + 1) + c5)) = (_Float16)g1[r];
            *reinterpret_cast<_Float16*>(lds + axX(s, grow, 32 * (cb0 + 2) + c5)) = (_Float16)g2[r];
            *reinterpret_cast<_Float16*>(lds + axX(s, grow, 32 * (cb0 + 3) + c5)) = (_Float16)g3[r];
        }
    }
    __syncthreads();

    // ---- MLP: 2 rounds of {h[64][256] (32x32) -> out^T partial (32x32)} ----
    f32x16 o00 = z16, o01 = z16, o10 = z16, o11 = z16;
    const int rbM = w & 1;
    const int cbp = (w >> 1) * 2;    // h col-tile pair
    const int ob0 = 2 * w;           // out ocol-tiles {2w, 2w+1}
    #pragma unroll
    for (int rk = 0; rk < 2; ++rk) {
        // h chunk: cols 256rk..+255
        f32x16 h0 = z16, h1 = z16;
        #pragma unroll
        for (int side = 0; side < 2; ++side) {
            const _Float16* up0 = UT + (size_t)(256 * rk + 32 * cbp + c5) * HH + side * 256;
            const _Float16* up1 = UT + (size_t)(256 * rk + 32 * (cbp + 1) + c5) * HH + side * 256;
            #pragma unroll
            for (int ks = 0; ks < 16; ++ks) {
                half8 ga = *reinterpret_cast<const half8*>(lds + axX(side, 32 * rbM + c5, 16 * ks + 8 * kg2));
                half8 u0 = ld8(up0 + 16 * ks + 8 * kg2);
                half8 u1 = ld8(up1 + 16 * ks + 8 * kg2);
                h0 = __builtin_amdgcn_mfma_f32_32x32x16_f16(ga, u0, h0, 0, 0, 0);
                h1 = __builtin_amdgcn_mfma_f32_32x32x16_f16(ga, u1, h1, 0, 0, 0);
            }
        }
        const float bb0 = b1[256 * rk + 32 * cbp + c5];
        const float bb1 = b1[256 * rk + 32 * (cbp + 1) + c5];
        #pragma unroll
        for (int r = 0; r < 16; ++r) {
            const int hrow = 32 * rbM + ROWF(r);
            *reinterpret_cast<_Float16*>(lds + axH2(hrow, 32 * cbp + c5)) =
                (_Float16)fmaxf(h0[r] + bb0, 0.f);
            *reinterpret_cast<_Float16*>(lds + axH2(hrow, 32 * (cbp + 1) + c5)) =
                (_Float16)fmaxf(h1[r] + bb1, 0.f);
        }
        __syncthreads();
        // out^T partial: K = this h chunk (local cols 0..255)
        __builtin_amdgcn_s_setprio(1);
        const _Float16* wp0 = W2T + (size_t)(32 * ob0 + c5) * HH + 256 * rk;
        const _Float16* wp1 = W2T + (size_t)(32 * (ob0 + 1) + c5) * HH + 256 * rk;
        #pragma unroll
        for (int ks = 0; ks < 16; ++ks) {
            half8 hb0 = *reinterpret_cast<const half8*>(lds + axH2(c5, 16 * ks + 8 * kg2));
            half8 hb1 = *reinterpret_cast<const half8*>(lds + axH2(32 + c5, 16 * ks + 8 * kg2));
            half8 wa0 = ld8(wp0 + 16 * ks + 8 * kg2);
            half8 wa1 = ld8(wp1 + 16 * ks + 8 * kg2);
            o00 = __builtin_amdgcn_mfma_f32_32x32x16_f16(wa0, hb0, o00, 0, 0, 0);
            o01 = __builtin_amdgcn_mfma_f32_32x32x16_f16(wa0, hb1, o01, 0, 0, 0);
            o10 = __builtin_amdgcn_mfma_f32_32x32x16_f16(wa1, hb0, o10, 0, 0, 0);
            o11 = __builtin_amdgcn_mfma_f32_32x32x16_f16(wa1, hb1, o11, 0, 0, 0);
        }
        __builtin_amdgcn_s_setprio(0);
        __syncthreads();
    }

    // ---- Epilogue: out^T regs -> float4 stores (4 consecutive ocols per quad) ----
    float* og = out + g * (size_t)(NB * HH);
    #pragma unroll
    for (int obi = 0; obi < 2; ++obi) {
        #pragma unroll
        for (int rq = 0; rq < 4; ++rq) {
            const int ocol0 = 32 * (ob0 + obi) + 8 * rq + 4 * kg2;
            const float4 b2v = *reinterpret_cast<const float4*>(b2 + ocol0);
            #pragma unroll
            for (int nb = 0; nb < 2; ++nb) {
                const f32x16& oc = obi ? (nb ? o11 : o10) : (nb ? o01 : o00);
                float4 res;
                res.x = oc[4 * rq + 0] + b2v.x;
                res.y = oc[4 * rq + 1] + b2v.y;
                res.z = oc[4 * rq + 2] + b2v.z;
                res.w = oc[4 * rq + 3] + b2v.w;
                *reinterpret_cast<float4*>(og + (size_t)(32 * nb + c5) * HH + ocol0) = res;
            }
        }
    }
    #undef ROWF
}

// ---------------- launch ----------------

extern "C" void kernel_launch(void* const* d_in, const int* in_sizes, int n_in,
                              void* d_out, int out_size, void* d_ws, size_t ws_size,
                              hipStream_t stream) {
    (void)in_sizes; (void)n_in; (void)out_size; (void)ws_size;
    const float* x1  = (const float*)d_in[0];
    const float* x2  = (const float*)d_in[1];
    const float* Wq1 = (const float*)d_in[2];
    const float* Wk1 = (const float*)d_in[3];
    const float* Wv1 = (const float*)d_in[4];
    const float* Wq2 = (const float*)d_in[5];
    const float* Wk2 = (const float*)d_in[6];
    const float* Wv2 = (const float*)d_in[7];
    const float* W1  = (const float*)d_in[8];
    const float* b1  = (const float*)d_in[9];
    const float* W2  = (const float*)d_in[10];
    const float* b2  = (const float*)d_in[11];
    float* out = (float*)d_out;

    char* ws = (char*)d_ws;
    _Float16* G1  = (_Float16*)(ws + 0);
    _Float16* G2  = (_Float16*)(ws + 131072);
    _Float16* UT  = (_Float16*)(ws + 262144);   // [512][512] combined
    _Float16* W2T = (_Float16*)(ws + 786432);

    const float scale = 0.0625f;  // D^-0.5

    prep_all<<<1792, 256, 0, stream>>>(Wq1, Wk1, Wv1, Wq2, Wk2, Wv2, W1, W2,
                                       G1, G2, UT, W2T, scale);
    fused_kernel<<<NGROUP, 512, 0, stream>>>(x1, x2, G1, G2, UT, W2T, b1, b2, out);
}

// Round 9
// 548.864 us; speedup vs baseline: 1.3093x; 1.3093x over previous
//
#include <hip/hip_runtime.h>
#include <stdint.h>

#define NB 64
#define DD 256
#define HH 512
#define NGROUP 2048

typedef __attribute__((ext_vector_type(8))) _Float16 half8;
typedef __attribute__((ext_vector_type(4))) _Float16 half4;
typedef __attribute__((ext_vector_type(4))) float f32x4;

__device__ __forceinline__ half8 ld8(const _Float16* p) {
    return *reinterpret_cast<const half8*>(p);
}

// ---------------- merged prep kernel (validated R7/R8) ----------------
__global__ void prep_all(const float* __restrict__ Wq1, const float* __restrict__ Wk1,
                         const float* __restrict__ Wv1, const float* __restrict__ Wq2,
                         const float* __restrict__ Wk2, const float* __restrict__ Wv2,
                         const float* __restrict__ W1, const float* __restrict__ W2,
                         _Float16* __restrict__ G1, _Float16* __restrict__ G2,
                         _Float16* __restrict__ UT, _Float16* __restrict__ W2T,
                         float scale) {
    const int b = blockIdx.x, t = threadIdx.x;
    if (b < 512) {
        const float* A = (b < 256) ? Wq1 : Wq2;
        const float* Bm = (b < 256) ? Wk2 : Wk1;
        _Float16* G = (b < 256) ? G1 : G2;
        const int d = b & 255, e = t;
        const float4* qa = reinterpret_cast<const float4*>(A + d * HH);
        const float4* ka = reinterpret_cast<const float4*>(Bm + e * HH);
        float s = 0.f;
        #pragma unroll 8
        for (int j = 0; j < HH / 4; ++j) {
            float4 a = qa[j], bb = ka[j];
            s += a.x * bb.x + a.y * bb.y + a.z * bb.z + a.w * bb.w;
        }
        G[d * DD + e] = (_Float16)(s * scale);
    } else if (b < 1536) {
        const int half = (b - 512) >> 9;
        const int o = (b - 512) & 511;
        const float* Wv = half ? Wv2 : Wv1;
        const float* W1p = W1 + half * HH * HH;
        const int d = t;
        const float4* va = reinterpret_cast<const float4*>(Wv + d * HH);
        float s = 0.f;
        #pragma unroll 4
        for (int j4 = 0; j4 < HH / 4; ++j4) {
            float4 a = va[j4];
            const int j = j4 * 4;
            s += a.x * W1p[(j + 0) * HH + o];
            s += a.y * W1p[(j + 1) * HH + o];
            s += a.z * W1p[(j + 2) * HH + o];
            s += a.w * W1p[(j + 3) * HH + o];
        }
        UT[o * HH + half * 256 + d] = (_Float16)s;
    } else {
        __shared__ float tile[32][33];
        const int bi = b - 1536;
        const int bk = (bi & 15) * 32;
        const int bh = (bi >> 4) * 32;
        const int tx = t & 31, ty = t >> 5;
        #pragma unroll
        for (int i = 0; i < 32; i += 8)
            tile[ty + i][tx] = W2[(bh + ty + i) * HH + bk + tx];
        __syncthreads();
        #pragma unroll
        for (int i = 0; i < 32; i += 8)
            W2T[(bk + ty + i) * HH + bh + tx] = (_Float16)tile[tx][ty + i];
    }
}

// ---------------- main fused kernel ----------------
// 512 thr (8 waves), 144 KiB LDS, 1 blk/CU. SEVEN coarse phases, SIX barriers.
// LDS:
//   X  @ 0       [2][64][256] f16, 512B rows, ext swz  -> becomes g1,g2
//   A  @ 65536   [2][64][256] f16 (A for score side s) -> XT [2][256][64] -> h [64][512]
//   P  @ 131072  [2][64][64] f16
// ext swz (>=512B rows): byte ^= ((row&7)<<4) ^ (((row>>3)&1)<<7)
// simple swz (128B rows): byte ^= ((row&7)<<4)

#define ABASE 65536
#define PBASE 131072

__device__ __forceinline__ int axX(int side, int row, int ec) {
    return side * 32768 + row * 512 +
           ((2 * ec) ^ ((row & 7) << 4) ^ (((row >> 3) & 1) << 7));
}
__device__ __forceinline__ int axA(int side, int row, int ec) {
    return ABASE + side * 32768 + row * 512 +
           ((2 * ec) ^ ((row & 7) << 4) ^ (((row >> 3) & 1) << 7));
}
__device__ __forceinline__ int axXT(int side, int row, int ec) {   // [256][64], 128B rows
    return ABASE + side * 32768 + row * 128 + ((2 * ec) ^ ((row & 7) << 4));
}
__device__ __forceinline__ int axH(int row, int ec) {              // [64][512], 1024B rows
    return ABASE + row * 1024 +
           ((2 * ec) ^ ((row & 7) << 4) ^ (((row >> 3) & 1) << 7));
}
__device__ __forceinline__ int axP(int side, int row, int ec) {    // [64][64], 128B rows
    return PBASE + side * 8192 + row * 128 + ((2 * ec) ^ ((row & 7) << 4));
}

__global__ __launch_bounds__(512, 1)
void fused_kernel(const float* __restrict__ x1g, const float* __restrict__ x2g,
                  const _Float16* __restrict__ G1, const _Float16* __restrict__ G2,
                  const _Float16* __restrict__ UT, const _Float16* __restrict__ W2T,
                  const float* __restrict__ b1, const float* __restrict__ b2,
                  float* __restrict__ out) {
    __shared__ __align__(16) char lds[147456];

    const int tid = threadIdx.x;
    const int lane = tid & 63;
    const int w = tid >> 6;        // wave 0..7
    const int c = lane & 15;
    const int kg = lane >> 4;
    const int s = w >> 2;          // side this wave serves
    const int wa = w & 3;
    const size_t g = blockIdx.x;
    const f32x4 z = {0.f, 0.f, 0.f, 0.f};

    // ==== P1: stage x -> f16 LDS (coalesced 1KB/instr reads) ====
    {
        const float* xs0 = x1g + g * (NB * DD);
        const float* xs1 = x2g + g * (NB * DD);
        #pragma unroll
        for (int it = 0; it < 8; ++it) {
            const int row = 8 * w + it;
            float4 a = reinterpret_cast<const float4*>(xs0 + row * DD)[lane];
            float4 b = reinterpret_cast<const float4*>(xs1 + row * DD)[lane];
            half4 ha, hb;
            ha[0] = (_Float16)a.x; ha[1] = (_Float16)a.y; ha[2] = (_Float16)a.z; ha[3] = (_Float16)a.w;
            hb[0] = (_Float16)b.x; hb[1] = (_Float16)b.y; hb[2] = (_Float16)b.z; hb[3] = (_Float16)b.w;
            *reinterpret_cast<half4*>(lds + axX(0, row, 4 * lane)) = ha;
            *reinterpret_cast<half4*>(lds + axX(1, row, 4 * lane)) = hb;
        }
    }
    __syncthreads();

    // ==== P2: A-full. slotA[s] = X_{1-s} @ Gsel^T, wave owns 64 d-cols ====
    // s=0: A2 = X2@G1^T (for S1); s=1: A1 = X1@G2^T (for S2)
    {
        const _Float16* Gsel = s ? G2 : G1;
        const int xo = 1 - s;
        f32x4 acc[4][4];
        #pragma unroll
        for (int i = 0; i < 4; ++i)
            #pragma unroll
            for (int ct = 0; ct < 4; ++ct) acc[i][ct] = z;
        #pragma unroll
        for (int ks = 0; ks < 8; ++ks) {
            half8 af[4];
            #pragma unroll
            for (int i = 0; i < 4; ++i)
                af[i] = *reinterpret_cast<const half8*>(lds + axX(xo, 16 * i + c, 32 * ks + 8 * kg));
            #pragma unroll
            for (int ct = 0; ct < 4; ++ct) {
                half8 bf = ld8(Gsel + (size_t)(64 * wa + 16 * ct + c) * DD + 32 * ks + 8 * kg);
                #pragma unroll
                for (int i = 0; i < 4; ++i)
                    acc[i][ct] = __builtin_amdgcn_mfma_f32_16x16x32_f16(af[i], bf, acc[i][ct], 0, 0, 0);
            }
        }
        #pragma unroll
        for (int i = 0; i < 4; ++i)
            #pragma unroll
            for (int ct = 0; ct < 4; ++ct)
                #pragma unroll
                for (int r = 0; r < 4; ++r)
                    *reinterpret_cast<_Float16*>(lds + axA(s, 16 * i + 4 * kg + r, 64 * wa + 16 * ct + c)) = (_Float16)acc[i][ct][r];
    }
    __syncthreads();

    // ==== P3: S (K=256) + softmax -> P[s]. wave owns rows 16wa of side s ====
    {
        f32x4 Sacc[4] = {z, z, z, z};
        #pragma unroll
        for (int ks = 0; ks < 8; ++ks) {
            half8 af = *reinterpret_cast<const half8*>(lds + axX(s, 16 * wa + c, 32 * ks + 8 * kg));
            #pragma unroll
            for (int j = 0; j < 4; ++j) {
                half8 bfr = *reinterpret_cast<const half8*>(lds + axA(s, 16 * j + c, 32 * ks + 8 * kg));
                Sacc[j] = __builtin_amdgcn_mfma_f32_16x16x32_f16(af, bfr, Sacc[j], 0, 0, 0);
            }
        }
        #pragma unroll
        for (int r = 0; r < 4; ++r) {
            float m0 = fmaxf(fmaxf(Sacc[0][r], Sacc[1][r]), fmaxf(Sacc[2][r], Sacc[3][r]));
            m0 = fmaxf(m0, __shfl_xor(m0, 1));
            m0 = fmaxf(m0, __shfl_xor(m0, 2));
            m0 = fmaxf(m0, __shfl_xor(m0, 4));
            m0 = fmaxf(m0, __shfl_xor(m0, 8));
            float e0 = __expf(Sacc[0][r] - m0);
            float e1 = __expf(Sacc[1][r] - m0);
            float e2 = __expf(Sacc[2][r] - m0);
            float e3 = __expf(Sacc[3][r] - m0);
            float s0 = e0 + e1 + e2 + e3;
            s0 += __shfl_xor(s0, 1);
            s0 += __shfl_xor(s0, 2);
            s0 += __shfl_xor(s0, 4);
            s0 += __shfl_xor(s0, 8);
            const float inv = 1.f / s0;
            const int row = 16 * wa + 4 * kg + r;
            *reinterpret_cast<_Float16*>(lds + axP(s, row, 16 * 0 + c)) = (_Float16)(e0 * inv);
            *reinterpret_cast<_Float16*>(lds + axP(s, row, 16 * 1 + c)) = (_Float16)(e1 * inv);
            *reinterpret_cast<_Float16*>(lds + axP(s, row, 16 * 2 + c)) = (_Float16)(e2 * inv);
            *reinterpret_cast<_Float16*>(lds + axP(s, row, 16 * 3 + c)) = (_Float16)(e3 * inv);
        }
    }
    __syncthreads();

    // ==== P4: XT build over slotA (A dead). wave transposes d-cols 64wa.. of X_s ====
    {
        #pragma unroll
        for (int jj = 0; jj < 8; ++jj) {
            half8 v = *reinterpret_cast<const half8*>(lds + axX(s, lane, 64 * wa + 8 * jj));
            #pragma unroll
            for (int e = 0; e < 8; ++e)
                *reinterpret_cast<_Float16*>(lds + axXT(s, 64 * wa + 8 * jj + e, lane)) = v[e];
        }
    }
    __syncthreads();

    // ==== P5: PV. g_s[:, 64wa..] = P_s @ X_s via XT; g overwrites X_s ====
    {
        half8 paf[4][2];
        #pragma unroll
        for (int i = 0; i < 4; ++i)
            #pragma unroll
            for (int ksp = 0; ksp < 2; ++ksp)
                paf[i][ksp] = *reinterpret_cast<const half8*>(lds + axP(s, 16 * i + c, 32 * ksp + 8 * kg));
        #pragma unroll
        for (int dt = 0; dt < 4; ++dt) {
            half8 bfr0 = *reinterpret_cast<const half8*>(lds + axXT(s, 64 * wa + 16 * dt + c, 8 * kg));
            half8 bfr1 = *reinterpret_cast<const half8*>(lds + axXT(s, 64 * wa + 16 * dt + c, 32 + 8 * kg));
            #pragma unroll
            for (int i = 0; i < 4; ++i) {
                f32x4 acc = z;
                acc = __builtin_amdgcn_mfma_f32_16x16x32_f16(paf[i][0], bfr0, acc, 0, 0, 0);
                acc = __builtin_amdgcn_mfma_f32_16x16x32_f16(paf[i][1], bfr1, acc, 0, 0, 0);
                #pragma unroll
                for (int r = 0; r < 4; ++r)
                    *reinterpret_cast<_Float16*>(lds + axX(s, 16 * i + 4 * kg + r, 64 * wa + 16 * dt + c)) = (_Float16)acc[r];
            }
        }
    }
    __syncthreads();

    // ==== P6: h-full = relu(gc @ Uc + b1) -> h[64][512] over A region ====
    {
        f32x4 acc[4][4];
        #pragma unroll
        for (int i = 0; i < 4; ++i)
            #pragma unroll
            for (int ct = 0; ct < 4; ++ct) acc[i][ct] = z;
        #pragma unroll
        for (int ks = 0; ks < 16; ++ks) {
            const int side = ks >> 3, kk = ks & 7;
            half8 af[4];
            #pragma unroll
            for (int i = 0; i < 4; ++i)
                af[i] = *reinterpret_cast<const half8*>(lds + axX(side, 16 * i + c, 32 * kk + 8 * kg));
            #pragma unroll
            for (int ct = 0; ct < 4; ++ct) {
                half8 bf = ld8(UT + (size_t)(64 * w + 16 * ct + c) * HH + side * 256 + 32 * kk + 8 * kg);
                #pragma unroll
                for (int i = 0; i < 4; ++i)
                    acc[i][ct] = __builtin_amdgcn_mfma_f32_16x16x32_f16(af[i], bf, acc[i][ct], 0, 0, 0);
            }
        }
        #pragma unroll
        for (int ct = 0; ct < 4; ++ct) {
            const float bb = b1[64 * w + 16 * ct + c];
            #pragma unroll
            for (int i = 0; i < 4; ++i)
                #pragma unroll
                for (int r = 0; r < 4; ++r)
                    *reinterpret_cast<_Float16*>(lds + axH(16 * i + 4 * kg + r, 64 * w + 16 * ct + c)) =
                        (_Float16)fmaxf(acc[i][ct][r] + bb, 0.f);
        }
    }
    __syncthreads();

    // ==== P7: out^T = W2T-rows x h (K=512) + b2, coalesced float4 stores ====
    {
        f32x4 oacc[4][4];
        #pragma unroll
        for (int i = 0; i < 4; ++i)
            #pragma unroll
            for (int nj = 0; nj < 4; ++nj) oacc[i][nj] = z;
        #pragma unroll
        for (int ks = 0; ks < 16; ++ks) {
            half8 bfr2[4];
            #pragma unroll
            for (int nj = 0; nj < 4; ++nj)
                bfr2[nj] = *reinterpret_cast<const half8*>(lds + axH(16 * nj + c, 32 * ks + 8 * kg));
            #pragma unroll
            for (int i = 0; i < 4; ++i) {
                half8 af2 = ld8(W2T + (size_t)(64 * w + 16 * i + c) * HH + 32 * ks + 8 * kg);
                #pragma unroll
                for (int nj = 0; nj < 4; ++nj)
                    oacc[i][nj] = __builtin_amdgcn_mfma_f32_16x16x32_f16(af2, bfr2[nj], oacc[i][nj], 0, 0, 0);
            }
        }
        float* og = out + g * (size_t)(NB * HH);
        #pragma unroll
        for (int i = 0; i < 4; ++i) {
            const int ocol0 = 64 * w + 16 * i + 4 * kg;
            const float4 b2v = *reinterpret_cast<const float4*>(b2 + ocol0);
            #pragma unroll
            for (int nj = 0; nj < 4; ++nj) {
                float4 res;
                res.x = oacc[i][nj][0] + b2v.x;
                res.y = oacc[i][nj][1] + b2v.y;
                res.z = oacc[i][nj][2] + b2v.z;
                res.w = oacc[i][nj][3] + b2v.w;
                *reinterpret_cast<float4*>(og + (size_t)(16 * nj + c) * HH + ocol0) = res;
            }
        }
    }
}

// ---------------- launch ----------------

extern "C" void kernel_launch(void* const* d_in, const int* in_sizes, int n_in,
                              void* d_out, int out_size, void* d_ws, size_t ws_size,
                              hipStream_t stream) {
    (void)in_sizes; (void)n_in; (void)out_size; (void)ws_size;
    const float* x1  = (const float*)d_in[0];
    const float* x2  = (const float*)d_in[1];
    const float* Wq1 = (const float*)d_in[2];
    const float* Wk1 = (const float*)d_in[3];
    const float* Wv1 = (const float*)d_in[4];
    const float* Wq2 = (const float*)d_in[5];
    const float* Wk2 = (const float*)d_in[6];
    const float* Wv2 = (const float*)d_in[7];
    const float* W1  = (const float*)d_in[8];
    const float* b1  = (const float*)d_in[9];
    const float* W2  = (const float*)d_in[10];
    const float* b2  = (const float*)d_in[11];
    float* out = (float*)d_out;

    char* ws = (char*)d_ws;
    _Float16* G1  = (_Float16*)(ws + 0);
    _Float16* G2  = (_Float16*)(ws + 131072);
    _Float16* UT  = (_Float16*)(ws + 262144);   // [512][512] combined
    _Float16* W2T = (_Float16*)(ws + 786432);

    const float scale = 0.0625f;  // D^-0.5

    prep_all<<<1792, 256, 0, stream>>>(Wq1, Wk1, Wv1, Wq2, Wk2, Wv2, W1, W2,
                                       G1, G2, UT, W2T, scale);
    fused_kernel<<<NGROUP, 512, 0, stream>>>(x1, x2, G1, G2, UT, W2T, b1, b2, out);
}

// Round 10
// 519.460 us; speedup vs baseline: 1.3834x; 1.0566x over previous
//
#include <hip/hip_runtime.h>
#include <stdint.h>

#define NB 64
#define DD 256
#define HH 512
#define NGROUP 2048

typedef __attribute__((ext_vector_type(8))) _Float16 half8;
typedef __attribute__((ext_vector_type(4))) _Float16 half4;
typedef __attribute__((ext_vector_type(4))) float f32x4;

__device__ __forceinline__ half8 ld8(const _Float16* p) {
    return *reinterpret_cast<const half8*>(p);
}

// ---------------- merged prep kernel (validated R7-R9) ----------------
__global__ void prep_all(const float* __restrict__ Wq1, const float* __restrict__ Wk1,
                         const float* __restrict__ Wv1, const float* __restrict__ Wq2,
                         const float* __restrict__ Wk2, const float* __restrict__ Wv2,
                         const float* __restrict__ W1, const float* __restrict__ W2,
                         _Float16* __restrict__ G1, _Float16* __restrict__ G2,
                         _Float16* __restrict__ UT, _Float16* __restrict__ W2T,
                         float scale) {
    const int b = blockIdx.x, t = threadIdx.x;
    if (b < 512) {
        const float* A = (b < 256) ? Wq1 : Wq2;
        const float* Bm = (b < 256) ? Wk2 : Wk1;
        _Float16* G = (b < 256) ? G1 : G2;
        const int d = b & 255, e = t;
        const float4* qa = reinterpret_cast<const float4*>(A + d * HH);
        const float4* ka = reinterpret_cast<const float4*>(Bm + e * HH);
        float s = 0.f;
        #pragma unroll 8
        for (int j = 0; j < HH / 4; ++j) {
            float4 a = qa[j], bb = ka[j];
            s += a.x * bb.x + a.y * bb.y + a.z * bb.z + a.w * bb.w;
        }
        G[d * DD + e] = (_Float16)(s * scale);
    } else if (b < 1536) {
        const int half = (b - 512) >> 9;
        const int o = (b - 512) & 511;
        const float* Wv = half ? Wv2 : Wv1;
        const float* W1p = W1 + half * HH * HH;
        const int d = t;
        const float4* va = reinterpret_cast<const float4*>(Wv + d * HH);
        float s = 0.f;
        #pragma unroll 4
        for (int j4 = 0; j4 < HH / 4; ++j4) {
            float4 a = va[j4];
            const int j = j4 * 4;
            s += a.x * W1p[(j + 0) * HH + o];
            s += a.y * W1p[(j + 1) * HH + o];
            s += a.z * W1p[(j + 2) * HH + o];
            s += a.w * W1p[(j + 3) * HH + o];
        }
        UT[o * HH + half * 256 + d] = (_Float16)s;
    } else {
        __shared__ float tile[32][33];
        const int bi = b - 1536;
        const int bk = (bi & 15) * 32;
        const int bh = (bi >> 4) * 32;
        const int tx = t & 31, ty = t >> 5;
        #pragma unroll
        for (int i = 0; i < 32; i += 8)
            tile[ty + i][tx] = W2[(bh + ty + i) * HH + bk + tx];
        __syncthreads();
        #pragma unroll
        for (int i = 0; i < 32; i += 8)
            W2T[(bk + ty + i) * HH + bh + tx] = (_Float16)tile[tx][ty + i];
    }
}

// ---------------- main fused kernel ----------------
// 1024 thr (16 waves), 144 KiB LDS, 1 blk/CU -> 4 waves/SIMD (VGPR<=128).
// Same 7-phase/6-barrier structure and LDS map as R9:
//   X  @ 0       [2][64][256] f16 ext-swz -> becomes g1,g2
//   A  @ 65536   [2][64][256] f16         -> XT [2][256][64] -> h [64][512]
//   P  @ 131072  [2][64][64] f16
#define ABASE 65536
#define PBASE 131072

__device__ __forceinline__ int axX(int side, int row, int ec) {
    return side * 32768 + row * 512 +
           ((2 * ec) ^ ((row & 7) << 4) ^ (((row >> 3) & 1) << 7));
}
__device__ __forceinline__ int axA(int side, int row, int ec) {
    return ABASE + side * 32768 + row * 512 +
           ((2 * ec) ^ ((row & 7) << 4) ^ (((row >> 3) & 1) << 7));
}
__device__ __forceinline__ int axXT(int side, int row, int ec) {   // [256][64], 128B rows
    return ABASE + side * 32768 + row * 128 + ((2 * ec) ^ ((row & 7) << 4));
}
__device__ __forceinline__ int axH(int row, int ec) {              // [64][512], 1024B rows
    return ABASE + row * 1024 +
           ((2 * ec) ^ ((row & 7) << 4) ^ (((row >> 3) & 1) << 7));
}
__device__ __forceinline__ int axP(int side, int row, int ec) {    // [64][64], 128B rows
    return PBASE + side * 8192 + row * 128 + ((2 * ec) ^ ((row & 7) << 4));
}

__global__ __launch_bounds__(1024, 4)
void fused_kernel(const float* __restrict__ x1g, const float* __restrict__ x2g,
                  const _Float16* __restrict__ G1, const _Float16* __restrict__ G2,
                  const _Float16* __restrict__ UT, const _Float16* __restrict__ W2T,
                  const float* __restrict__ b1, const float* __restrict__ b2,
                  float* __restrict__ out) {
    __shared__ __align__(16) char lds[147456];

    const int tid = threadIdx.x;
    const int lane = tid & 63;
    const int w = tid >> 6;        // wave 0..15
    const int c = lane & 15;
    const int kg = lane >> 4;
    const int s = w >> 3;          // side this wave serves (waves 0-7: side0, 8-15: side1)
    const int ws = w & 7;          // 32-wide strip index within side
    const size_t g = blockIdx.x;
    const f32x4 z = {0.f, 0.f, 0.f, 0.f};

    // ==== P1: stage x -> f16 LDS (each wave: 4 rows, both sides) ====
    {
        const float* xs0 = x1g + g * (NB * DD);
        const float* xs1 = x2g + g * (NB * DD);
        #pragma unroll
        for (int it = 0; it < 4; ++it) {
            const int row = 4 * w + it;
            float4 a = reinterpret_cast<const float4*>(xs0 + row * DD)[lane];
            float4 b = reinterpret_cast<const float4*>(xs1 + row * DD)[lane];
            half4 ha, hb;
            ha[0] = (_Float16)a.x; ha[1] = (_Float16)a.y; ha[2] = (_Float16)a.z; ha[3] = (_Float16)a.w;
            hb[0] = (_Float16)b.x; hb[1] = (_Float16)b.y; hb[2] = (_Float16)b.z; hb[3] = (_Float16)b.w;
            *reinterpret_cast<half4*>(lds + axX(0, row, 4 * lane)) = ha;
            *reinterpret_cast<half4*>(lds + axX(1, row, 4 * lane)) = hb;
        }
    }
    __syncthreads();

    // ==== P2: A-full. slotA[s] = X_{1-s} @ Gsel^T; wave owns 32 d-cols ====
    {
        const _Float16* Gsel = s ? G2 : G1;
        const int xo = 1 - s;
        f32x4 acc[4][2];
        #pragma unroll
        for (int i = 0; i < 4; ++i) { acc[i][0] = z; acc[i][1] = z; }
        #pragma unroll
        for (int ks = 0; ks < 8; ++ks) {
            half8 af[4];
            #pragma unroll
            for (int i = 0; i < 4; ++i)
                af[i] = *reinterpret_cast<const half8*>(lds + axX(xo, 16 * i + c, 32 * ks + 8 * kg));
            #pragma unroll
            for (int ct = 0; ct < 2; ++ct) {
                half8 bf = ld8(Gsel + (size_t)(32 * ws + 16 * ct + c) * DD + 32 * ks + 8 * kg);
                #pragma unroll
                for (int i = 0; i < 4; ++i)
                    acc[i][ct] = __builtin_amdgcn_mfma_f32_16x16x32_f16(af[i], bf, acc[i][ct], 0, 0, 0);
            }
        }
        #pragma unroll
        for (int i = 0; i < 4; ++i)
            #pragma unroll
            for (int ct = 0; ct < 2; ++ct)
                #pragma unroll
                for (int r = 0; r < 4; ++r)
                    *reinterpret_cast<_Float16*>(lds + axA(s, 16 * i + 4 * kg + r, 32 * ws + 16 * ct + c)) = (_Float16)acc[i][ct][r];
    }
    __syncthreads();

    // ==== P3: S (K=256) + softmax -> P[s]; 8 active waves (4 per side) ====
    if ((w & 4) == 0) {
        const int wa = w & 3;
        f32x4 Sacc[4] = {z, z, z, z};
        #pragma unroll
        for (int ks = 0; ks < 8; ++ks) {
            half8 af = *reinterpret_cast<const half8*>(lds + axX(s, 16 * wa + c, 32 * ks + 8 * kg));
            #pragma unroll
            for (int j = 0; j < 4; ++j) {
                half8 bfr = *reinterpret_cast<const half8*>(lds + axA(s, 16 * j + c, 32 * ks + 8 * kg));
                Sacc[j] = __builtin_amdgcn_mfma_f32_16x16x32_f16(af, bfr, Sacc[j], 0, 0, 0);
            }
        }
        #pragma unroll
        for (int r = 0; r < 4; ++r) {
            float m0 = fmaxf(fmaxf(Sacc[0][r], Sacc[1][r]), fmaxf(Sacc[2][r], Sacc[3][r]));
            m0 = fmaxf(m0, __shfl_xor(m0, 1));
            m0 = fmaxf(m0, __shfl_xor(m0, 2));
            m0 = fmaxf(m0, __shfl_xor(m0, 4));
            m0 = fmaxf(m0, __shfl_xor(m0, 8));
            float e0 = __expf(Sacc[0][r] - m0);
            float e1 = __expf(Sacc[1][r] - m0);
            float e2 = __expf(Sacc[2][r] - m0);
            float e3 = __expf(Sacc[3][r] - m0);
            float s0 = e0 + e1 + e2 + e3;
            s0 += __shfl_xor(s0, 1);
            s0 += __shfl_xor(s0, 2);
            s0 += __shfl_xor(s0, 4);
            s0 += __shfl_xor(s0, 8);
            const float inv = 1.f / s0;
            const int row = 16 * wa + 4 * kg + r;
            *reinterpret_cast<_Float16*>(lds + axP(s, row, 16 * 0 + c)) = (_Float16)(e0 * inv);
            *reinterpret_cast<_Float16*>(lds + axP(s, row, 16 * 1 + c)) = (_Float16)(e1 * inv);
            *reinterpret_cast<_Float16*>(lds + axP(s, row, 16 * 2 + c)) = (_Float16)(e2 * inv);
            *reinterpret_cast<_Float16*>(lds + axP(s, row, 16 * 3 + c)) = (_Float16)(e3 * inv);
        }
    }
    __syncthreads();

    // ==== P4: XT build over slotA (A dead); wave transposes 32 d-cols of X_s ====
    {
        #pragma unroll
        for (int jj = 0; jj < 4; ++jj) {
            half8 v = *reinterpret_cast<const half8*>(lds + axX(s, lane, 32 * ws + 8 * jj));
            #pragma unroll
            for (int e = 0; e < 8; ++e)
                *reinterpret_cast<_Float16*>(lds + axXT(s, 32 * ws + 8 * jj + e, lane)) = v[e];
        }
    }
    __syncthreads();

    // ==== P5: PV. g_s[:, 32ws..] = P_s @ X_s via XT; g overwrites X_s ====
    {
        half8 paf[4][2];
        #pragma unroll
        for (int i = 0; i < 4; ++i)
            #pragma unroll
            for (int ksp = 0; ksp < 2; ++ksp)
                paf[i][ksp] = *reinterpret_cast<const half8*>(lds + axP(s, 16 * i + c, 32 * ksp + 8 * kg));
        #pragma unroll
        for (int dt = 0; dt < 2; ++dt) {
            half8 bfr0 = *reinterpret_cast<const half8*>(lds + axXT(s, 32 * ws + 16 * dt + c, 8 * kg));
            half8 bfr1 = *reinterpret_cast<const half8*>(lds + axXT(s, 32 * ws + 16 * dt + c, 32 + 8 * kg));
            #pragma unroll
            for (int i = 0; i < 4; ++i) {
                f32x4 acc = z;
                acc = __builtin_amdgcn_mfma_f32_16x16x32_f16(paf[i][0], bfr0, acc, 0, 0, 0);
                acc = __builtin_amdgcn_mfma_f32_16x16x32_f16(paf[i][1], bfr1, acc, 0, 0, 0);
                #pragma unroll
                for (int r = 0; r < 4; ++r)
                    *reinterpret_cast<_Float16*>(lds + axX(s, 16 * i + 4 * kg + r, 32 * ws + 16 * dt + c)) = (_Float16)acc[r];
            }
        }
    }
    __syncthreads();

    // ==== P6: h-full = relu(g @ U + b1) -> h[64][512] over A region; wave: 32 h-cols ====
    {
        f32x4 acc[4][2];
        #pragma unroll
        for (int i = 0; i < 4; ++i) { acc[i][0] = z; acc[i][1] = z; }
        #pragma unroll
        for (int ks = 0; ks < 16; ++ks) {
            const int side = ks >> 3, kk = ks & 7;
            half8 af[4];
            #pragma unroll
            for (int i = 0; i < 4; ++i)
                af[i] = *reinterpret_cast<const half8*>(lds + axX(side, 16 * i + c, 32 * kk + 8 * kg));
            #pragma unroll
            for (int ct = 0; ct < 2; ++ct) {
                half8 bf = ld8(UT + (size_t)(32 * w + 16 * ct + c) * HH + side * 256 + 32 * kk + 8 * kg);
                #pragma unroll
                for (int i = 0; i < 4; ++i)
                    acc[i][ct] = __builtin_amdgcn_mfma_f32_16x16x32_f16(af[i], bf, acc[i][ct], 0, 0, 0);
            }
        }
        #pragma unroll
        for (int ct = 0; ct < 2; ++ct) {
            const float bb = b1[32 * w + 16 * ct + c];
            #pragma unroll
            for (int i = 0; i < 4; ++i)
                #pragma unroll
                for (int r = 0; r < 4; ++r)
                    *reinterpret_cast<_Float16*>(lds + axH(16 * i + 4 * kg + r, 32 * w + 16 * ct + c)) =
                        (_Float16)fmaxf(acc[i][ct][r] + bb, 0.f);
        }
    }
    __syncthreads();

    // ==== P7: out^T = W2T-rows x h (K=512) + b2; wave: 32 ocols ====
    {
        f32x4 oacc[2][4];
        #pragma unroll
        for (int i = 0; i < 2; ++i)
            #pragma unroll
            for (int nj = 0; nj < 4; ++nj) oacc[i][nj] = z;
        #pragma unroll
        for (int ks = 0; ks < 16; ++ks) {
            half8 bfr2[4];
            #pragma unroll
            for (int nj = 0; nj < 4; ++nj)
                bfr2[nj] = *reinterpret_cast<const half8*>(lds + axH(16 * nj + c, 32 * ks + 8 * kg));
            #pragma unroll
            for (int i = 0; i < 2; ++i) {
                half8 af2 = ld8(W2T + (size_t)(32 * w + 16 * i + c) * HH + 32 * ks + 8 * kg);
                #pragma unroll
                for (int nj = 0; nj < 4; ++nj)
                    oacc[i][nj] = __builtin_amdgcn_mfma_f32_16x16x32_f16(af2, bfr2[nj], oacc[i][nj], 0, 0, 0);
            }
        }
        float* og = out + g * (size_t)(NB * HH);
        #pragma unroll
        for (int i = 0; i < 2; ++i) {
            const int ocol0 = 32 * w + 16 * i + 4 * kg;
            const float4 b2v = *reinterpret_cast<const float4*>(b2 + ocol0);
            #pragma unroll
            for (int nj = 0; nj < 4; ++nj) {
                float4 res;
                res.x = oacc[i][nj][0] + b2v.x;
                res.y = oacc[i][nj][1] + b2v.y;
                res.z = oacc[i][nj][2] + b2v.z;
                res.w = oacc[i][nj][3] + b2v.w;
                *reinterpret_cast<float4*>(og + (size_t)(16 * nj + c) * HH + ocol0) = res;
            }
        }
    }
}

// ---------------- launch ----------------

extern "C" void kernel_launch(void* const* d_in, const int* in_sizes, int n_in,
                              void* d_out, int out_size, void* d_ws, size_t ws_size,
                              hipStream_t stream) {
    (void)in_sizes; (void)n_in; (void)out_size; (void)ws_size;
    const float* x1  = (const float*)d_in[0];
    const float* x2  = (const float*)d_in[1];
    const float* Wq1 = (const float*)d_in[2];
    const float* Wk1 = (const float*)d_in[3];
    const float* Wv1 = (const float*)d_in[4];
    const float* Wq2 = (const float*)d_in[5];
    const float* Wk2 = (const float*)d_in[6];
    const float* Wv2 = (const float*)d_in[7];
    const float* W1  = (const float*)d_in[8];
    const float* b1  = (const float*)d_in[9];
    const float* W2  = (const float*)d_in[10];
    const float* b2  = (const float*)d_in[11];
    float* out = (float*)d_out;

    char* ws = (char*)d_ws;
    _Float16* G1  = (_Float16*)(ws + 0);
    _Float16* G2  = (_Float16*)(ws + 131072);
    _Float16* UT  = (_Float16*)(ws + 262144);   // [512][512] combined
    _Float16* W2T = (_Float16*)(ws + 786432);

    const float scale = 0.0625f;  // D^-0.5

    prep_all<<<1792, 256, 0, stream>>>(Wq1, Wk1, Wv1, Wq2, Wk2, Wv2, W1, W2,
                                       G1, G2, UT, W2T, scale);
    fused_kernel<<<NGROUP, 1024, 0, stream>>>(x1, x2, G1, G2, UT, W2T, b1, b2, out);
}